// Round 12
// baseline (210.673 us; speedup 1.0000x reference)
//
#include <hip/hip_runtime.h>
#include <hip/hip_bf16.h>

// ---------------------------------------------------------------------------
// Wide&Deep forward.
// prep: fused deep-convert + 5 weight transposes.
// L1: gemm_hi — 128x256, BK=32, 48KB LDS dbuf -> 2 blocks/CU (inter-block
//     overlap experiment, resource-audited: no spill possible).
// L2: gemm_2c — 256x256 (R9 schedule, control).
// tower: fused L3->L4->L5->head megakernel (R11, proven).
// ---------------------------------------------------------------------------

typedef __attribute__((ext_vector_type(8))) short short8;
typedef __attribute__((ext_vector_type(4))) float f32x4;

static __device__ __forceinline__ unsigned short f2bf_bits(float x) {
  __hip_bfloat16 h = __float2bfloat16(x);
  return __builtin_bit_cast(unsigned short, h);
}
static __device__ __forceinline__ float bf_bits2f(unsigned short u) {
  __hip_bfloat16 h = __builtin_bit_cast(__hip_bfloat16, u);
  return __bfloat162float(h);
}

static __device__ __forceinline__ void gload16(const void* g, void* l) {
  __builtin_amdgcn_global_load_lds(
      (const __attribute__((address_space(1))) void*)g,
      (__attribute__((address_space(3))) void*)l, 16, 0, 0);
}

#define MFMA16(a, b, c) __builtin_amdgcn_mfma_f32_16x16x32_bf16((a), (b), (c), 0, 0, 0)
#define PRIO(x) __builtin_amdgcn_s_setprio(x)
#define BAR() __builtin_amdgcn_s_barrier()
#define MEMFENCE() asm volatile("" ::: "memory")

// ---------------------------------------------------------------------------
// prep: blocks [0,8192): deep f32->bf16; [8192,9440): weight transposes.
// ---------------------------------------------------------------------------
__global__ __launch_bounds__(256) void prep(
    const float* __restrict__ deep, unsigned short* __restrict__ deepb,
    const float* __restrict__ W1, __hip_bfloat16* __restrict__ W1t,
    const float* __restrict__ W2, __hip_bfloat16* __restrict__ W2t,
    const float* __restrict__ W3, __hip_bfloat16* __restrict__ W3t,
    const float* __restrict__ Wd1, __hip_bfloat16* __restrict__ Wd1t,
    const float* __restrict__ Wd2, __hip_bfloat16* __restrict__ Wd2t) {
  __shared__ float tile[64][65];
  int blk = blockIdx.x;
  if (blk < 8192) {
    int i = blk * 256 + threadIdx.x;
    const f32x4* p = (const f32x4*)deep + (size_t)i * 2;
    f32x4 a = p[0], b = p[1];
    short8 o;
    o[0] = (short)f2bf_bits(a[0]); o[1] = (short)f2bf_bits(a[1]);
    o[2] = (short)f2bf_bits(a[2]); o[3] = (short)f2bf_bits(a[3]);
    o[4] = (short)f2bf_bits(b[0]); o[5] = (short)f2bf_bits(b[1]);
    o[6] = (short)f2bf_bits(b[2]); o[7] = (short)f2bf_bits(b[3]);
    *(short8*)(deepb + (size_t)i * 8) = o;
    return;
  }
  blk -= 8192;
  const float* W; __hip_bfloat16* Wt; int K, N;
  if (blk < 512)       {             W = W1;  Wt = W1t;  K = 1024; N = 2048; }
  else if (blk < 1024) { blk -= 512;  W = W2;  Wt = W2t;  K = 2048; N = 1024; }
  else if (blk < 1152) { blk -= 1024; W = W3;  Wt = W3t;  K = 1024; N = 512; }
  else if (blk < 1216) { blk -= 1152; W = Wd1; Wt = Wd1t; K = 512;  N = 512; }
  else                 { blk -= 1216; W = Wd2; Wt = Wd2t; K = 512;  N = 256; }
  const int ntx = N >> 6;
  const int k0 = (blk / ntx) * 64;
  const int n0 = (blk % ntx) * 64;
  const int t  = threadIdx.x;
  const int tn = t & 63;
  const int t4 = t >> 6;
#pragma unroll
  for (int p = 0; p < 16; ++p) {
    int kl = p * 4 + t4;
    tile[kl][tn] = W[(size_t)(k0 + kl) * N + (n0 + tn)];
  }
  __syncthreads();
#pragma unroll
  for (int p = 0; p < 16; ++p) {
    int nl = p * 4 + t4;
    Wt[(size_t)(n0 + nl) * K + (k0 + tn)] = __float2bfloat16(tile[tn][nl]);
  }
}

// ---------------------------------------------------------------------------
// gemm_hi: 128x256, BK=32, 256 threads (4 waves 2x2, wave-tile 64x128),
// dbuf LDS 48KB -> 2 blocks/CU. Simple 2-barrier counted-vmcnt loop:
//   iter t: [stage(t+1) -> buf^1]; vmcnt(6) [t's 6 loads retired]; BAR
//   (publish t; WAR: buf^1's last reads at t-1 retired pre-trailing-BAR);
//   frag reads (12 b128); MFMA x32; BAR.
// Frag/swizzle scheme identical to tower's BK=32 loop (proven):
//   staged [row][64B], chunk f-XOR f(r)=(r>>1)&3, pre-swizzled source.
// ---------------------------------------------------------------------------
__global__ __launch_bounds__(256, 2) void gemm_hi(
    const __hip_bfloat16* __restrict__ A,
    const __hip_bfloat16* __restrict__ Bt,
    const float* __restrict__ bias,
    __hip_bfloat16* __restrict__ Cb,
    float* __restrict__ Cf,
    int N, int K, int nbx) {
  __shared__ char lds[49152];  // buf b: A @ b*24576 (8KB), B @ +8192 (16KB)

  const int tid  = threadIdx.x;
  const int lane = tid & 63;
  const int wid  = tid >> 6;       // 0..3
  const int wmr  = wid >> 1;       // 0..1 : rows wmr*64
  const int wnc  = wid & 1;        // 0..1 : cols wnc*128

  const int nwg = gridDim.x;
  const int cpx = nwg >> 3;
  const int id  = blockIdx.x;
  const int swz = (id & 7) * cpx + (id >> 3);
  const int bm  = (swz / nbx) * 128;
  const int bn  = (swz % nbx) * 256;

  const int ln15 = lane & 15;
  const int kq   = lane >> 4;      // 0..3
  const unsigned csel = (unsigned)(((unsigned)kq ^ (unsigned)((ln15 >> 1) & 3)) << 4);

  const int srow = tid >> 2;       // 0..63
  const int sc   = (tid & 3) ^ ((tid >> 3) & 3);
  const __hip_bfloat16* baseA = A  + (size_t)(bm + srow) * K + sc * 8;
  const __hip_bfloat16* baseB = Bt + (size_t)(bn + srow) * K + sc * 8;

  const int nt = K >> 5;

  auto stage = [&](int kt) {
    char* dst = lds + (kt & 1) * 24576;
#pragma unroll
    for (int q = 0; q < 2; ++q)
      gload16(baseA + (size_t)((q * 64) * K + kt * 32), dst + q * 4096 + tid * 16);
#pragma unroll
    for (int q = 0; q < 4; ++q)
      gload16(baseB + (size_t)((q * 64) * K + kt * 32),
              dst + 8192 + q * 4096 + tid * 16);
  };

  auto LD = [&](unsigned off) -> short8 { return *(const short8*)&lds[off]; };

  f32x4 acc[4][8] = {};

  stage(0);
  for (int t = 0; t < nt; ++t) {
    if (t + 1 < nt) {
      stage(t + 1);
      asm volatile("s_waitcnt vmcnt(6)");
    } else {
      asm volatile("s_waitcnt vmcnt(0)");
    }
    BAR(); MEMFENCE();
    const unsigned pb = (unsigned)((t & 1) * 24576);
    short8 aF[4], bF[8];
#pragma unroll
    for (int mi = 0; mi < 4; ++mi)
      aF[mi] = LD(pb + (unsigned)((wmr * 64 + mi * 16 + ln15) * 64) + csel);
#pragma unroll
    for (int nj = 0; nj < 8; ++nj)
      bF[nj] = LD(pb + 8192u + (unsigned)((wnc * 128 + nj * 16 + ln15) * 64) + csel);
    PRIO(1);
#pragma unroll
    for (int mi = 0; mi < 4; ++mi)
#pragma unroll
      for (int nj = 0; nj < 8; ++nj)
        acc[mi][nj] = MFMA16(aF[mi], bF[nj], acc[mi][nj]);
    PRIO(0);
    BAR(); MEMFENCE();
  }

  float biasv[8];
#pragma unroll
  for (int nj = 0; nj < 8; ++nj)
    biasv[nj] = bias[bn + wnc * 128 + nj * 16 + ln15];

#pragma unroll
  for (int mi = 0; mi < 4; ++mi) {
    int row0 = bm + wmr * 64 + mi * 16 + kq * 4;
#pragma unroll
    for (int nj = 0; nj < 8; ++nj) {
      int col = bn + wnc * 128 + nj * 16 + ln15;
#pragma unroll
      for (int r = 0; r < 4; ++r) {
        float v = acc[mi][nj][r] + biasv[nj];
        v = v > 0.f ? v : 0.f;
        size_t idx = (size_t)(row0 + r) * N + col;
        Cb[idx] = __float2bfloat16(v);
        if (Cf) Cf[idx] = v;
      }
    }
  }
}

// ---------------------------------------------------------------------------
// gemm_2c: 256x256, BK=64, 8 waves 2x4, 16x16x32 MFMA, R9 schedule (control).
// ---------------------------------------------------------------------------
__global__ __launch_bounds__(512, 2) void gemm_2c(
    const __hip_bfloat16* __restrict__ A,
    const __hip_bfloat16* __restrict__ Bt,
    const float* __restrict__ bias,
    __hip_bfloat16* __restrict__ Cb,
    float* __restrict__ Cf,
    int N, int K, int nbx) {
  __shared__ char lds[131072];

  const int tid  = threadIdx.x;
  const int lane = tid & 63;
  const int wid  = tid >> 6;
  const int wm   = wid >> 2;
  const int wn   = wid & 3;

  const int nwg = gridDim.x;
  const int cpx = nwg >> 3;
  const int id  = blockIdx.x;
  const int swz = (id & 7) * cpx + (id >> 3);
  const int bm  = (swz / nbx) * 256;
  const int bn  = (swz % nbx) * 256;

  const int ln15 = lane & 15;
  const unsigned aoff = (unsigned)((wm * 128 + ln15) * 128) +
                        (unsigned)((((lane >> 4) ^ (lane & 7)) << 4));
  const unsigned boff = 32768u + (unsigned)((wn * 64 + ln15) * 128) +
                        (unsigned)((((lane >> 4) ^ (lane & 7)) << 4));

  const int nt = K >> 6;

  const __hip_bfloat16* baseA = A  + (size_t)(bm + (tid >> 3)) * K +
                                ((tid & 7) ^ ((tid >> 3) & 7)) * 8;
  const __hip_bfloat16* baseB = Bt + (size_t)(bn + (tid >> 3)) * K +
                                ((tid & 7) ^ ((tid >> 3) & 7)) * 8;
  const unsigned ldst0 = (unsigned)(wid * 1024);

  auto stage = [&](int kt, int half, int isB) {
    const __hip_bfloat16* base = isB ? baseB : baseA;
    char* dst = lds + ((kt & 1) * 65536) + (isB ? 32768 : 0) + half * 16384;
#pragma unroll
    for (int q = 0; q < 2; ++q) {
      gload16(base + (size_t)((half * 128 + q * 64) * K + kt * 64),
              dst + q * 8192 + ldst0);
    }
  };

  auto LD = [&](unsigned off) -> short8 {
    return *(const short8*)&lds[off];
  };

  f32x4 acc[8][4] = {};
  short8 aLo[4][2], aHi[4][2], b0v[2][2], b1v[2][2];

  stage(0, 0, 1); stage(0, 1, 1); stage(0, 0, 0); stage(0, 1, 0);
  if (nt > 1) {
    stage(1, 0, 1); stage(1, 1, 1); stage(1, 0, 0); stage(1, 1, 0);
    asm volatile("s_waitcnt vmcnt(8)");
  } else {
    asm volatile("s_waitcnt vmcnt(0)");
  }
  BAR();
  MEMFENCE();
#pragma unroll
  for (int mi = 0; mi < 4; ++mi)
#pragma unroll
    for (int kk = 0; kk < 2; ++kk)
      aLo[mi][kk] = LD((aoff + (unsigned)(mi * 2048)) ^ (unsigned)(kk << 6));
#pragma unroll
  for (int nj = 0; nj < 2; ++nj)
#pragma unroll
    for (int kk = 0; kk < 2; ++kk)
      b0v[nj][kk] = LD((boff + (unsigned)(nj * 2048)) ^ (unsigned)(kk << 6));

  for (int t = 0; t < nt; ++t) {
    const unsigned po = (unsigned)(t & 1) * 65536u;
    const unsigned pn = po ^ 65536u;

    // ---- P1 ----
#pragma unroll
    for (int nj = 0; nj < 2; ++nj)
#pragma unroll
      for (int kk = 0; kk < 2; ++kk)
        b1v[nj][kk] = LD((po + boff + (unsigned)((nj + 2) * 2048)) ^ (unsigned)(kk << 6));
    PRIO(1);
#pragma unroll
    for (int kk = 0; kk < 2; ++kk)
#pragma unroll
      for (int mi = 0; mi < 4; ++mi)
#pragma unroll
        for (int nj = 0; nj < 2; ++nj)
          acc[mi][nj] = MFMA16(aLo[mi][kk], b0v[nj][kk], acc[mi][nj]);
    PRIO(0);

    // ---- P2 ----
#pragma unroll
    for (int mi = 0; mi < 4; ++mi)
#pragma unroll
      for (int kk = 0; kk < 2; ++kk)
        aHi[mi][kk] = LD((po + aoff + (unsigned)((mi + 4) * 2048)) ^ (unsigned)(kk << 6));
    PRIO(1);
#pragma unroll
    for (int kk = 0; kk < 2; ++kk)
#pragma unroll
      for (int mi = 0; mi < 4; ++mi)
#pragma unroll
        for (int nj = 0; nj < 2; ++nj)
          acc[mi][nj + 2] = MFMA16(aLo[mi][kk], b1v[nj][kk], acc[mi][nj + 2]);
    PRIO(0);
    BAR();
    MEMFENCE();

    // ---- P3 ----
    PRIO(1);
#pragma unroll
    for (int kk = 0; kk < 2; ++kk)
#pragma unroll
      for (int mi = 0; mi < 4; ++mi)
#pragma unroll
        for (int nj = 0; nj < 2; ++nj)
          acc[mi + 4][nj] = MFMA16(aHi[mi][kk], b0v[nj][kk], acc[mi + 4][nj]);
    PRIO(0);
    if (t + 2 < nt) { stage(t + 2, 0, 1); stage(t + 2, 1, 1); }
    if (t + 1 < nt) {
      if (t + 2 < nt) asm volatile("s_waitcnt vmcnt(4)");
      else            asm volatile("s_waitcnt vmcnt(0)");
      BAR();
      MEMFENCE();
    }

    // ---- P4 ----
    if (t + 1 < nt) {
#pragma unroll
      for (int mi = 0; mi < 4; ++mi)
#pragma unroll
        for (int kk = 0; kk < 2; ++kk)
          aLo[mi][kk] = LD((pn + aoff + (unsigned)(mi * 2048)) ^ (unsigned)(kk << 6));
#pragma unroll
      for (int nj = 0; nj < 2; ++nj)
#pragma unroll
        for (int kk = 0; kk < 2; ++kk)
          b0v[nj][kk] = LD((pn + boff + (unsigned)(nj * 2048)) ^ (unsigned)(kk << 6));
    }
    PRIO(1);
#pragma unroll
    for (int kk = 0; kk < 2; ++kk)
#pragma unroll
      for (int mi = 0; mi < 4; ++mi)
#pragma unroll
        for (int nj = 0; nj < 2; ++nj)
          acc[mi + 4][nj + 2] = MFMA16(aHi[mi][kk], b1v[nj][kk], acc[mi + 4][nj + 2]);
    PRIO(0);
    if (t + 2 < nt) { stage(t + 2, 0, 0); stage(t + 2, 1, 0); }
  }

  float biasv[4];
#pragma unroll
  for (int nj = 0; nj < 4; ++nj)
    biasv[nj] = bias[bn + wn * 64 + nj * 16 + ln15];

#pragma unroll
  for (int mi = 0; mi < 8; ++mi) {
    int row0 = bm + wm * 128 + mi * 16 + (lane >> 4) * 4;
#pragma unroll
    for (int nj = 0; nj < 4; ++nj) {
      int col = bn + wn * 64 + nj * 16 + ln15;
#pragma unroll
      for (int r = 0; r < 4; ++r) {
        float v = acc[mi][nj][r] + biasv[nj];
        v = v > 0.f ? v : 0.f;
        size_t idx = (size_t)(row0 + r) * N + col;
        Cb[idx] = __float2bfloat16(v);
        if (Cf) Cf[idx] = v;
      }
    }
  }
}

// ---------------------------------------------------------------------------
// tower: fused L3 -> L4 -> L5 -> head (unchanged from R11).
// ---------------------------------------------------------------------------
__global__ __launch_bounds__(512, 2) void tower(
    const __hip_bfloat16* __restrict__ H2,
    const __hip_bfloat16* __restrict__ W3t, const float* __restrict__ b3,
    const __hip_bfloat16* __restrict__ Wd1t, const float* __restrict__ bd1,
    const __hip_bfloat16* __restrict__ Wd2t, const float* __restrict__ bd2,
    float* __restrict__ Sf, float* __restrict__ Df,
    const float* __restrict__ wide, const int* __restrict__ dom,
    const float* __restrict__ Wh, const float* __restrict__ bh,
    float* __restrict__ outp) {
  __shared__ char lds[139264];
  const int tid  = threadIdx.x;
  const int lane = tid & 63;
  const int wid  = tid >> 6;
  const int ln15 = lane & 15;
  const int kq   = lane >> 4;

  const int id  = blockIdx.x;
  const int swz = (id & 7) * 32 + (id >> 3);
  const int bm  = swz * 64;

  const unsigned csel = (unsigned)(((unsigned)kq ^ (unsigned)((ln15 >> 1) & 3)) << 4);
  const int sc   = (tid & 3) ^ ((tid >> 3) & 3);
  const int srow = tid >> 2;

  auto LD = [&](unsigned off) -> short8 { return *(const short8*)&lds[off]; };

  // ---------------- L3 ----------------
  auto stage3 = [&](int kt) {
    int half = kt & 1;
#pragma unroll
    for (int q = 0; q < 4; ++q)
      gload16(W3t + (size_t)(q * 128 + srow) * 1024 + kt * 32 + sc * 8,
              lds + 73728 + half * 32768 + q * 8192 + tid * 16);
    if (tid < 256)
      gload16(H2 + (size_t)(bm + srow) * 1024 + kt * 32 + sc * 8,
              lds + 65536 + half * 4096 + tid * 16);
  };

  f32x4 acc3[4][4] = {};
  stage3(0);
  for (int t = 0; t < 32; ++t) {
    if (t + 1 < 32) {
      stage3(t + 1);
      if (wid < 4) asm volatile("s_waitcnt vmcnt(5)");
      else         asm volatile("s_waitcnt vmcnt(4)");
    } else {
      asm volatile("s_waitcnt vmcnt(0)");
    }
    BAR(); MEMFENCE();
    const unsigned pa = 65536u + (unsigned)((t & 1) * 4096);
    const unsigned pb = 73728u + (unsigned)((t & 1) * 32768);
    short8 aF[4], bF[4];
#pragma unroll
    for (int mi = 0; mi < 4; ++mi)
      aF[mi] = LD(pa + (unsigned)((mi * 16 + ln15) * 64) + csel);
#pragma unroll
    for (int nj = 0; nj < 4; ++nj)
      bF[nj] = LD(pb + (unsigned)((wid * 64 + nj * 16 + ln15) * 64) + csel);
    PRIO(1);
#pragma unroll
    for (int mi = 0; mi < 4; ++mi)
#pragma unroll
      for (int nj = 0; nj < 4; ++nj)
        acc3[mi][nj] = MFMA16(aF[mi], bF[nj], acc3[mi][nj]);
    PRIO(0);
    BAR(); MEMFENCE();
  }

  {
    float bv[4];
#pragma unroll
    for (int nj = 0; nj < 4; ++nj) bv[nj] = b3[wid * 64 + nj * 16 + ln15];
#pragma unroll
    for (int mi = 0; mi < 4; ++mi) {
      int lrow = mi * 16 + kq * 4;
#pragma unroll
      for (int nj = 0; nj < 4; ++nj) {
        int col = wid * 64 + nj * 16 + ln15;
#pragma unroll
        for (int r = 0; r < 4; ++r) {
          float v = acc3[mi][nj][r] + bv[nj];
          v = v > 0.f ? v : 0.f;
          Sf[(size_t)(bm + lrow + r) * 512 + col] = v;
          int rr = lrow + r;
          *(unsigned short*)&lds[rr * 1024 + (((col >> 3) ^ (rr & 7)) << 4) +
                                 (col & 7) * 2] = f2bf_bits(v);
        }
      }
    }
  }

  // ---------------- L4 ----------------
  auto stage4 = [&](int kt) {
    int half = kt & 1;
#pragma unroll
    for (int q = 0; q < 4; ++q)
      gload16(Wd1t + (size_t)(q * 128 + srow) * 512 + kt * 32 + sc * 8,
              lds + 73728 + half * 32768 + q * 8192 + tid * 16);
  };
  stage4(0);
  asm volatile("s_waitcnt lgkmcnt(0)");
  BAR(); MEMFENCE();

  f32x4 acc4[4][4] = {};
  for (int t = 0; t < 16; ++t) {
    if (t + 1 < 16) { stage4(t + 1); asm volatile("s_waitcnt vmcnt(4)"); }
    else            { asm volatile("s_waitcnt vmcnt(0)"); }
    BAR(); MEMFENCE();
    const unsigned pb = 73728u + (unsigned)((t & 1) * 32768);
    short8 aF[4], bF[4];
#pragma unroll
    for (int mi = 0; mi < 4; ++mi) {
      int rr = mi * 16 + ln15;
      aF[mi] = LD((unsigned)(rr * 1024) +
                  (unsigned)((((t * 4 + kq) ^ (rr & 7)) << 4)));
    }
#pragma unroll
    for (int nj = 0; nj < 4; ++nj)
      bF[nj] = LD(pb + (unsigned)((wid * 64 + nj * 16 + ln15) * 64) + csel);
    PRIO(1);
#pragma unroll
    for (int mi = 0; mi < 4; ++mi)
#pragma unroll
      for (int nj = 0; nj < 4; ++nj)
        acc4[mi][nj] = MFMA16(aF[mi], bF[nj], acc4[mi][nj]);
    PRIO(0);
    BAR(); MEMFENCE();
  }

  {
    float bv[4];
#pragma unroll
    for (int nj = 0; nj < 4; ++nj) bv[nj] = bd1[wid * 64 + nj * 16 + ln15];
#pragma unroll
    for (int mi = 0; mi < 4; ++mi) {
      int lrow = mi * 16 + kq * 4;
#pragma unroll
      for (int nj = 0; nj < 4; ++nj) {
        int col = wid * 64 + nj * 16 + ln15;
#pragma unroll
        for (int r = 0; r < 4; ++r) {
          float v = acc4[mi][nj][r] + bv[nj];
          v = v > 0.f ? v : 0.f;
          int rr = lrow + r;
          *(unsigned short*)&lds[rr * 1024 + (((col >> 3) ^ (rr & 7)) << 4) +
                                 (col & 7) * 2] = f2bf_bits(v);
        }
      }
    }
  }

  // ---------------- L5 ----------------
  auto stage5 = [&](int kt) {
    int half = kt & 1;
#pragma unroll
    for (int q = 0; q < 2; ++q)
      gload16(Wd2t + (size_t)(q * 128 + srow) * 512 + kt * 32 + sc * 8,
              lds + 73728 + half * 16384 + q * 8192 + tid * 16);
  };
  stage5(0);
  asm volatile("s_waitcnt lgkmcnt(0)");
  BAR(); MEMFENCE();

  f32x4 acc5[4][2] = {};
  for (int t = 0; t < 16; ++t) {
    if (t + 1 < 16) { stage5(t + 1); asm volatile("s_waitcnt vmcnt(2)"); }
    else            { asm volatile("s_waitcnt vmcnt(0)"); }
    BAR(); MEMFENCE();
    const unsigned pb = 73728u + (unsigned)((t & 1) * 16384);
    short8 aF[4], bF[2];
#pragma unroll
    for (int mi = 0; mi < 4; ++mi) {
      int rr = mi * 16 + ln15;
      aF[mi] = LD((unsigned)(rr * 1024) +
                  (unsigned)((((t * 4 + kq) ^ (rr & 7)) << 4)));
    }
#pragma unroll
    for (int nj = 0; nj < 2; ++nj)
      bF[nj] = LD(pb + (unsigned)((wid * 32 + nj * 16 + ln15) * 64) + csel);
    PRIO(1);
#pragma unroll
    for (int mi = 0; mi < 4; ++mi)
#pragma unroll
      for (int nj = 0; nj < 2; ++nj)
        acc5[mi][nj] = MFMA16(aF[mi], bF[nj], acc5[mi][nj]);
    PRIO(0);
    BAR(); MEMFENCE();
  }

  unsigned short* ldsD = (unsigned short*)(lds + 65536);
  {
    float bv[2];
#pragma unroll
    for (int nj = 0; nj < 2; ++nj) bv[nj] = bd2[wid * 32 + nj * 16 + ln15];
#pragma unroll
    for (int mi = 0; mi < 4; ++mi) {
      int lrow = mi * 16 + kq * 4;
#pragma unroll
      for (int nj = 0; nj < 2; ++nj) {
        int col = wid * 32 + nj * 16 + ln15;
#pragma unroll
        for (int r = 0; r < 4; ++r) {
          float v = acc5[mi][nj][r] + bv[nj];
          v = v > 0.f ? v : 0.f;
          Df[(size_t)(bm + lrow + r) * 256 + col] = v;
          ldsD[(lrow + r) * 264 + col] = f2bf_bits(v);
        }
      }
    }
  }
  asm volatile("s_waitcnt lgkmcnt(0)");
  BAR(); MEMFENCE();

  // ---------------- head ----------------
  const int hrow = tid >> 3;
  const int he   = tid & 7;
  float s = 0.f;
  {
    const f32x4* wp = (const f32x4*)(wide + (size_t)(bm + hrow) * 256 + he * 32);
#pragma unroll
    for (int j = 0; j < 8; ++j) {
      f32x4 w = wp[j];
      s += w[0] + w[1] + w[2] + w[3];
    }
  }
  const int dm = dom[bm + hrow];
  {
    const f32x4* hp = (const f32x4*)(Wh + (size_t)dm * 256 + he * 32);
    const short8* dp = (const short8*)(ldsD + hrow * 264 + he * 32);
#pragma unroll
    for (int j = 0; j < 4; ++j) {
      short8 d8 = dp[j];
      f32x4 h0 = hp[2 * j], h1 = hp[2 * j + 1];
      s += bf_bits2f((unsigned short)d8[0]) * h0[0] +
           bf_bits2f((unsigned short)d8[1]) * h0[1] +
           bf_bits2f((unsigned short)d8[2]) * h0[2] +
           bf_bits2f((unsigned short)d8[3]) * h0[3] +
           bf_bits2f((unsigned short)d8[4]) * h1[0] +
           bf_bits2f((unsigned short)d8[5]) * h1[1] +
           bf_bits2f((unsigned short)d8[6]) * h1[2] +
           bf_bits2f((unsigned short)d8[7]) * h1[3];
    }
  }
  float* ldsH = (float*)(lds + 100352);
  ldsH[hrow * 8 + he] = s;
  asm volatile("s_waitcnt lgkmcnt(0)");
  BAR(); MEMFENCE();

  if (tid < 64) {
    float v = 0.f;
#pragma unroll
    for (int j = 0; j < 8; ++j) v += ldsH[tid * 8 + j];
    int dmr = dom[bm + tid];
    float x = v + bh[dmr];
    outp[bm + tid] = 1.f / (1.f + __expf(-x));
  }
}

// ---------------------------------------------------------------------------
extern "C" void kernel_launch(void* const* d_in, const int* in_sizes, int n_in,
                              void* d_out, int out_size, void* d_ws, size_t ws_size,
                              hipStream_t stream) {
  const float* wide = (const float*)d_in[0];
  const float* deep = (const float*)d_in[1];
  const int*   dom  = (const int*)d_in[2];
  const float* W1  = (const float*)d_in[3];
  const float* b1  = (const float*)d_in[4];
  const float* W2  = (const float*)d_in[5];
  const float* b2  = (const float*)d_in[6];
  const float* W3  = (const float*)d_in[7];
  const float* b3  = (const float*)d_in[8];
  const float* Wd1 = (const float*)d_in[9];
  const float* bd1 = (const float*)d_in[10];
  const float* Wd2 = (const float*)d_in[11];
  const float* bd2 = (const float*)d_in[12];
  const float* Wh  = (const float*)d_in[13];
  const float* bh  = (const float*)d_in[14];
  float* out = (float*)d_out;

  const int B = 16384;
  char* ws = (char*)d_ws;
  __hip_bfloat16* buf0 = (__hip_bfloat16*)ws;
  __hip_bfloat16* buf1 = (__hip_bfloat16*)(ws + 33554432ull);
  __hip_bfloat16* W1t  = (__hip_bfloat16*)(ws + 100663296ull);
  __hip_bfloat16* W2t  = W1t + 2048 * 1024;
  __hip_bfloat16* W3t  = W2t + 1024 * 2048;
  __hip_bfloat16* Wd1t = W3t + 512 * 1024;
  __hip_bfloat16* Wd2t = Wd1t + 512 * 512;

  prep<<<dim3(8192 + 1248), 256, 0, stream>>>(
      deep, (unsigned short*)buf0, W1, W1t, W2, W2t, W3, W3t, Wd1, Wd1t, Wd2, Wd2t);

  float* shared_out = out + B;
  float* d_out_f    = out + B + (size_t)B * 512;

  // L1: [B,1024]x[1024,2048] -> H1 (buf1)   [gemm_hi, 1024 blocks, 2/CU]
  gemm_hi<<<dim3((B / 128) * (2048 / 256)), 256, 0, stream>>>(
      buf0, W1t, b1, buf1, nullptr, 2048, 1024, 2048 / 256);
  // L2: [B,2048]x[2048,1024] -> H2 (buf0)   [gemm_2c control]
  gemm_2c<<<dim3((1024 / 256) * (B / 256)), 512, 0, stream>>>(
      buf1, W2t, b2, buf0, nullptr, 1024, 2048, 1024 / 256);
  // L3+L4+L5+head fused
  tower<<<dim3(256), 512, 0, stream>>>(
      buf0, W3t, b3, Wd1t, bd1, Wd2t, bd2,
      shared_out, d_out_f, wide, dom, Wh, bh, out);
}

// Round 13
// 200.031 us; speedup vs baseline: 1.0532x; 1.0532x over previous
//
#include <hip/hip_runtime.h>
#include <hip/hip_bf16.h>

// ---------------------------------------------------------------------------
// Wide&Deep forward (best-known configuration, R11).
// prep: fused deep-convert + 5 weight transposes.
// L1/L2: gemm_2c (256x256, 16x16x32, 2-barrier deep-prefetch schedule).
// tower: fused L3->L4->L5->head megakernel.
// ---------------------------------------------------------------------------

typedef __attribute__((ext_vector_type(8))) short short8;
typedef __attribute__((ext_vector_type(4))) float f32x4;

static __device__ __forceinline__ unsigned short f2bf_bits(float x) {
  __hip_bfloat16 h = __float2bfloat16(x);
  return __builtin_bit_cast(unsigned short, h);
}
static __device__ __forceinline__ float bf_bits2f(unsigned short u) {
  __hip_bfloat16 h = __builtin_bit_cast(__hip_bfloat16, u);
  return __bfloat162float(h);
}

static __device__ __forceinline__ void gload16(const void* g, void* l) {
  __builtin_amdgcn_global_load_lds(
      (const __attribute__((address_space(1))) void*)g,
      (__attribute__((address_space(3))) void*)l, 16, 0, 0);
}

#define MFMA16(a, b, c) __builtin_amdgcn_mfma_f32_16x16x32_bf16((a), (b), (c), 0, 0, 0)
#define PRIO(x) __builtin_amdgcn_s_setprio(x)
#define BAR() __builtin_amdgcn_s_barrier()
#define MEMFENCE() asm volatile("" ::: "memory")

// ---------------------------------------------------------------------------
// prep: blocks [0,8192): deep f32->bf16; [8192,9440): weight transposes.
// ---------------------------------------------------------------------------
__global__ __launch_bounds__(256) void prep(
    const float* __restrict__ deep, unsigned short* __restrict__ deepb,
    const float* __restrict__ W1, __hip_bfloat16* __restrict__ W1t,
    const float* __restrict__ W2, __hip_bfloat16* __restrict__ W2t,
    const float* __restrict__ W3, __hip_bfloat16* __restrict__ W3t,
    const float* __restrict__ Wd1, __hip_bfloat16* __restrict__ Wd1t,
    const float* __restrict__ Wd2, __hip_bfloat16* __restrict__ Wd2t) {
  __shared__ float tile[64][65];
  int blk = blockIdx.x;
  if (blk < 8192) {
    int i = blk * 256 + threadIdx.x;
    const f32x4* p = (const f32x4*)deep + (size_t)i * 2;
    f32x4 a = p[0], b = p[1];
    short8 o;
    o[0] = (short)f2bf_bits(a[0]); o[1] = (short)f2bf_bits(a[1]);
    o[2] = (short)f2bf_bits(a[2]); o[3] = (short)f2bf_bits(a[3]);
    o[4] = (short)f2bf_bits(b[0]); o[5] = (short)f2bf_bits(b[1]);
    o[6] = (short)f2bf_bits(b[2]); o[7] = (short)f2bf_bits(b[3]);
    *(short8*)(deepb + (size_t)i * 8) = o;
    return;
  }
  blk -= 8192;
  const float* W; __hip_bfloat16* Wt; int K, N;
  if (blk < 512)       {             W = W1;  Wt = W1t;  K = 1024; N = 2048; }
  else if (blk < 1024) { blk -= 512;  W = W2;  Wt = W2t;  K = 2048; N = 1024; }
  else if (blk < 1152) { blk -= 1024; W = W3;  Wt = W3t;  K = 1024; N = 512; }
  else if (blk < 1216) { blk -= 1152; W = Wd1; Wt = Wd1t; K = 512;  N = 512; }
  else                 { blk -= 1216; W = Wd2; Wt = Wd2t; K = 512;  N = 256; }
  const int ntx = N >> 6;
  const int k0 = (blk / ntx) * 64;
  const int n0 = (blk % ntx) * 64;
  const int t  = threadIdx.x;
  const int tn = t & 63;
  const int t4 = t >> 6;
#pragma unroll
  for (int p = 0; p < 16; ++p) {
    int kl = p * 4 + t4;
    tile[kl][tn] = W[(size_t)(k0 + kl) * N + (n0 + tn)];
  }
  __syncthreads();
#pragma unroll
  for (int p = 0; p < 16; ++p) {
    int nl = p * 4 + t4;
    Wt[(size_t)(n0 + nl) * K + (k0 + tn)] = __float2bfloat16(tile[tn][nl]);
  }
}

// ---------------------------------------------------------------------------
// gemm_2c: 256x256, BK=64, 8 waves 2x4, 16x16x32 MFMA, R9 schedule.
// ---------------------------------------------------------------------------
__global__ __launch_bounds__(512, 2) void gemm_2c(
    const __hip_bfloat16* __restrict__ A,
    const __hip_bfloat16* __restrict__ Bt,
    const float* __restrict__ bias,
    __hip_bfloat16* __restrict__ Cb,
    float* __restrict__ Cf,
    int N, int K, int nbx) {
  __shared__ char lds[131072];

  const int tid  = threadIdx.x;
  const int lane = tid & 63;
  const int wid  = tid >> 6;
  const int wm   = wid >> 2;
  const int wn   = wid & 3;

  const int nwg = gridDim.x;
  const int cpx = nwg >> 3;
  const int id  = blockIdx.x;
  const int swz = (id & 7) * cpx + (id >> 3);
  const int bm  = (swz / nbx) * 256;
  const int bn  = (swz % nbx) * 256;

  const int ln15 = lane & 15;
  const unsigned aoff = (unsigned)((wm * 128 + ln15) * 128) +
                        (unsigned)((((lane >> 4) ^ (lane & 7)) << 4));
  const unsigned boff = 32768u + (unsigned)((wn * 64 + ln15) * 128) +
                        (unsigned)((((lane >> 4) ^ (lane & 7)) << 4));

  const int nt = K >> 6;

  const __hip_bfloat16* baseA = A  + (size_t)(bm + (tid >> 3)) * K +
                                ((tid & 7) ^ ((tid >> 3) & 7)) * 8;
  const __hip_bfloat16* baseB = Bt + (size_t)(bn + (tid >> 3)) * K +
                                ((tid & 7) ^ ((tid >> 3) & 7)) * 8;
  const unsigned ldst0 = (unsigned)(wid * 1024);

  auto stage = [&](int kt, int half, int isB) {
    const __hip_bfloat16* base = isB ? baseB : baseA;
    char* dst = lds + ((kt & 1) * 65536) + (isB ? 32768 : 0) + half * 16384;
#pragma unroll
    for (int q = 0; q < 2; ++q) {
      gload16(base + (size_t)((half * 128 + q * 64) * K + kt * 64),
              dst + q * 8192 + ldst0);
    }
  };

  auto LD = [&](unsigned off) -> short8 {
    return *(const short8*)&lds[off];
  };

  f32x4 acc[8][4] = {};
  short8 aLo[4][2], aHi[4][2], b0v[2][2], b1v[2][2];

  stage(0, 0, 1); stage(0, 1, 1); stage(0, 0, 0); stage(0, 1, 0);
  if (nt > 1) {
    stage(1, 0, 1); stage(1, 1, 1); stage(1, 0, 0); stage(1, 1, 0);
    asm volatile("s_waitcnt vmcnt(8)");
  } else {
    asm volatile("s_waitcnt vmcnt(0)");
  }
  BAR();
  MEMFENCE();
#pragma unroll
  for (int mi = 0; mi < 4; ++mi)
#pragma unroll
    for (int kk = 0; kk < 2; ++kk)
      aLo[mi][kk] = LD((aoff + (unsigned)(mi * 2048)) ^ (unsigned)(kk << 6));
#pragma unroll
  for (int nj = 0; nj < 2; ++nj)
#pragma unroll
    for (int kk = 0; kk < 2; ++kk)
      b0v[nj][kk] = LD((boff + (unsigned)(nj * 2048)) ^ (unsigned)(kk << 6));

  for (int t = 0; t < nt; ++t) {
    const unsigned po = (unsigned)(t & 1) * 65536u;
    const unsigned pn = po ^ 65536u;

    // ---- P1 ----
#pragma unroll
    for (int nj = 0; nj < 2; ++nj)
#pragma unroll
      for (int kk = 0; kk < 2; ++kk)
        b1v[nj][kk] = LD((po + boff + (unsigned)((nj + 2) * 2048)) ^ (unsigned)(kk << 6));
    PRIO(1);
#pragma unroll
    for (int kk = 0; kk < 2; ++kk)
#pragma unroll
      for (int mi = 0; mi < 4; ++mi)
#pragma unroll
        for (int nj = 0; nj < 2; ++nj)
          acc[mi][nj] = MFMA16(aLo[mi][kk], b0v[nj][kk], acc[mi][nj]);
    PRIO(0);

    // ---- P2 ----
#pragma unroll
    for (int mi = 0; mi < 4; ++mi)
#pragma unroll
      for (int kk = 0; kk < 2; ++kk)
        aHi[mi][kk] = LD((po + aoff + (unsigned)((mi + 4) * 2048)) ^ (unsigned)(kk << 6));
    PRIO(1);
#pragma unroll
    for (int kk = 0; kk < 2; ++kk)
#pragma unroll
      for (int mi = 0; mi < 4; ++mi)
#pragma unroll
        for (int nj = 0; nj < 2; ++nj)
          acc[mi][nj + 2] = MFMA16(aLo[mi][kk], b1v[nj][kk], acc[mi][nj + 2]);
    PRIO(0);
    BAR();
    MEMFENCE();

    // ---- P3 ----
    PRIO(1);
#pragma unroll
    for (int kk = 0; kk < 2; ++kk)
#pragma unroll
      for (int mi = 0; mi < 4; ++mi)
#pragma unroll
        for (int nj = 0; nj < 2; ++nj)
          acc[mi + 4][nj] = MFMA16(aHi[mi][kk], b0v[nj][kk], acc[mi + 4][nj]);
    PRIO(0);
    if (t + 2 < nt) { stage(t + 2, 0, 1); stage(t + 2, 1, 1); }
    if (t + 1 < nt) {
      if (t + 2 < nt) asm volatile("s_waitcnt vmcnt(4)");
      else            asm volatile("s_waitcnt vmcnt(0)");
      BAR();
      MEMFENCE();
    }

    // ---- P4 ----
    if (t + 1 < nt) {
#pragma unroll
      for (int mi = 0; mi < 4; ++mi)
#pragma unroll
        for (int kk = 0; kk < 2; ++kk)
          aLo[mi][kk] = LD((pn + aoff + (unsigned)(mi * 2048)) ^ (unsigned)(kk << 6));
#pragma unroll
      for (int nj = 0; nj < 2; ++nj)
#pragma unroll
        for (int kk = 0; kk < 2; ++kk)
          b0v[nj][kk] = LD((pn + boff + (unsigned)(nj * 2048)) ^ (unsigned)(kk << 6));
    }
    PRIO(1);
#pragma unroll
    for (int kk = 0; kk < 2; ++kk)
#pragma unroll
      for (int mi = 0; mi < 4; ++mi)
#pragma unroll
        for (int nj = 0; nj < 2; ++nj)
          acc[mi + 4][nj + 2] = MFMA16(aHi[mi][kk], b1v[nj][kk], acc[mi + 4][nj + 2]);
    PRIO(0);
    if (t + 2 < nt) { stage(t + 2, 0, 0); stage(t + 2, 1, 0); }
  }

  float biasv[4];
#pragma unroll
  for (int nj = 0; nj < 4; ++nj)
    biasv[nj] = bias[bn + wn * 64 + nj * 16 + ln15];

#pragma unroll
  for (int mi = 0; mi < 8; ++mi) {
    int row0 = bm + wm * 128 + mi * 16 + (lane >> 4) * 4;
#pragma unroll
    for (int nj = 0; nj < 4; ++nj) {
      int col = bn + wn * 64 + nj * 16 + ln15;
#pragma unroll
      for (int r = 0; r < 4; ++r) {
        float v = acc[mi][nj][r] + biasv[nj];
        v = v > 0.f ? v : 0.f;
        size_t idx = (size_t)(row0 + r) * N + col;
        Cb[idx] = __float2bfloat16(v);
        if (Cf) Cf[idx] = v;
      }
    }
  }
}

// ---------------------------------------------------------------------------
// tower: fused L3 -> L4 -> L5 -> head (R11, proven).
// ---------------------------------------------------------------------------
__global__ __launch_bounds__(512, 2) void tower(
    const __hip_bfloat16* __restrict__ H2,
    const __hip_bfloat16* __restrict__ W3t, const float* __restrict__ b3,
    const __hip_bfloat16* __restrict__ Wd1t, const float* __restrict__ bd1,
    const __hip_bfloat16* __restrict__ Wd2t, const float* __restrict__ bd2,
    float* __restrict__ Sf, float* __restrict__ Df,
    const float* __restrict__ wide, const int* __restrict__ dom,
    const float* __restrict__ Wh, const float* __restrict__ bh,
    float* __restrict__ outp) {
  __shared__ char lds[139264];
  const int tid  = threadIdx.x;
  const int lane = tid & 63;
  const int wid  = tid >> 6;
  const int ln15 = lane & 15;
  const int kq   = lane >> 4;

  const int id  = blockIdx.x;
  const int swz = (id & 7) * 32 + (id >> 3);
  const int bm  = swz * 64;

  const unsigned csel = (unsigned)(((unsigned)kq ^ (unsigned)((ln15 >> 1) & 3)) << 4);
  const int sc   = (tid & 3) ^ ((tid >> 3) & 3);
  const int srow = tid >> 2;

  auto LD = [&](unsigned off) -> short8 { return *(const short8*)&lds[off]; };

  // ---------------- L3 ----------------
  auto stage3 = [&](int kt) {
    int half = kt & 1;
#pragma unroll
    for (int q = 0; q < 4; ++q)
      gload16(W3t + (size_t)(q * 128 + srow) * 1024 + kt * 32 + sc * 8,
              lds + 73728 + half * 32768 + q * 8192 + tid * 16);
    if (tid < 256)
      gload16(H2 + (size_t)(bm + srow) * 1024 + kt * 32 + sc * 8,
              lds + 65536 + half * 4096 + tid * 16);
  };

  f32x4 acc3[4][4] = {};
  stage3(0);
  for (int t = 0; t < 32; ++t) {
    if (t + 1 < 32) {
      stage3(t + 1);
      if (wid < 4) asm volatile("s_waitcnt vmcnt(5)");
      else         asm volatile("s_waitcnt vmcnt(4)");
    } else {
      asm volatile("s_waitcnt vmcnt(0)");
    }
    BAR(); MEMFENCE();
    const unsigned pa = 65536u + (unsigned)((t & 1) * 4096);
    const unsigned pb = 73728u + (unsigned)((t & 1) * 32768);
    short8 aF[4], bF[4];
#pragma unroll
    for (int mi = 0; mi < 4; ++mi)
      aF[mi] = LD(pa + (unsigned)((mi * 16 + ln15) * 64) + csel);
#pragma unroll
    for (int nj = 0; nj < 4; ++nj)
      bF[nj] = LD(pb + (unsigned)((wid * 64 + nj * 16 + ln15) * 64) + csel);
    PRIO(1);
#pragma unroll
    for (int mi = 0; mi < 4; ++mi)
#pragma unroll
      for (int nj = 0; nj < 4; ++nj)
        acc3[mi][nj] = MFMA16(aF[mi], bF[nj], acc3[mi][nj]);
    PRIO(0);
    BAR(); MEMFENCE();
  }

  {
    float bv[4];
#pragma unroll
    for (int nj = 0; nj < 4; ++nj) bv[nj] = b3[wid * 64 + nj * 16 + ln15];
#pragma unroll
    for (int mi = 0; mi < 4; ++mi) {
      int lrow = mi * 16 + kq * 4;
#pragma unroll
      for (int nj = 0; nj < 4; ++nj) {
        int col = wid * 64 + nj * 16 + ln15;
#pragma unroll
        for (int r = 0; r < 4; ++r) {
          float v = acc3[mi][nj][r] + bv[nj];
          v = v > 0.f ? v : 0.f;
          Sf[(size_t)(bm + lrow + r) * 512 + col] = v;
          int rr = lrow + r;
          *(unsigned short*)&lds[rr * 1024 + (((col >> 3) ^ (rr & 7)) << 4) +
                                 (col & 7) * 2] = f2bf_bits(v);
        }
      }
    }
  }

  // ---------------- L4 ----------------
  auto stage4 = [&](int kt) {
    int half = kt & 1;
#pragma unroll
    for (int q = 0; q < 4; ++q)
      gload16(Wd1t + (size_t)(q * 128 + srow) * 512 + kt * 32 + sc * 8,
              lds + 73728 + half * 32768 + q * 8192 + tid * 16);
  };
  stage4(0);
  asm volatile("s_waitcnt lgkmcnt(0)");
  BAR(); MEMFENCE();

  f32x4 acc4[4][4] = {};
  for (int t = 0; t < 16; ++t) {
    if (t + 1 < 16) { stage4(t + 1); asm volatile("s_waitcnt vmcnt(4)"); }
    else            { asm volatile("s_waitcnt vmcnt(0)"); }
    BAR(); MEMFENCE();
    const unsigned pb = 73728u + (unsigned)((t & 1) * 32768);
    short8 aF[4], bF[4];
#pragma unroll
    for (int mi = 0; mi < 4; ++mi) {
      int rr = mi * 16 + ln15;
      aF[mi] = LD((unsigned)(rr * 1024) +
                  (unsigned)((((t * 4 + kq) ^ (rr & 7)) << 4)));
    }
#pragma unroll
    for (int nj = 0; nj < 4; ++nj)
      bF[nj] = LD(pb + (unsigned)((wid * 64 + nj * 16 + ln15) * 64) + csel);
    PRIO(1);
#pragma unroll
    for (int mi = 0; mi < 4; ++mi)
#pragma unroll
      for (int nj = 0; nj < 4; ++nj)
        acc4[mi][nj] = MFMA16(aF[mi], bF[nj], acc4[mi][nj]);
    PRIO(0);
    BAR(); MEMFENCE();
  }

  {
    float bv[4];
#pragma unroll
    for (int nj = 0; nj < 4; ++nj) bv[nj] = bd1[wid * 64 + nj * 16 + ln15];
#pragma unroll
    for (int mi = 0; mi < 4; ++mi) {
      int lrow = mi * 16 + kq * 4;
#pragma unroll
      for (int nj = 0; nj < 4; ++nj) {
        int col = wid * 64 + nj * 16 + ln15;
#pragma unroll
        for (int r = 0; r < 4; ++r) {
          float v = acc4[mi][nj][r] + bv[nj];
          v = v > 0.f ? v : 0.f;
          int rr = lrow + r;
          *(unsigned short*)&lds[rr * 1024 + (((col >> 3) ^ (rr & 7)) << 4) +
                                 (col & 7) * 2] = f2bf_bits(v);
        }
      }
    }
  }

  // ---------------- L5 ----------------
  auto stage5 = [&](int kt) {
    int half = kt & 1;
#pragma unroll
    for (int q = 0; q < 2; ++q)
      gload16(Wd2t + (size_t)(q * 128 + srow) * 512 + kt * 32 + sc * 8,
              lds + 73728 + half * 16384 + q * 8192 + tid * 16);
  };
  stage5(0);
  asm volatile("s_waitcnt lgkmcnt(0)");
  BAR(); MEMFENCE();

  f32x4 acc5[4][2] = {};
  for (int t = 0; t < 16; ++t) {
    if (t + 1 < 16) { stage5(t + 1); asm volatile("s_waitcnt vmcnt(2)"); }
    else            { asm volatile("s_waitcnt vmcnt(0)"); }
    BAR(); MEMFENCE();
    const unsigned pb = 73728u + (unsigned)((t & 1) * 16384);
    short8 aF[4], bF[2];
#pragma unroll
    for (int mi = 0; mi < 4; ++mi) {
      int rr = mi * 16 + ln15;
      aF[mi] = LD((unsigned)(rr * 1024) +
                  (unsigned)((((t * 4 + kq) ^ (rr & 7)) << 4)));
    }
#pragma unroll
    for (int nj = 0; nj < 2; ++nj)
      bF[nj] = LD(pb + (unsigned)((wid * 32 + nj * 16 + ln15) * 64) + csel);
    PRIO(1);
#pragma unroll
    for (int mi = 0; mi < 4; ++mi)
#pragma unroll
      for (int nj = 0; nj < 2; ++nj)
        acc5[mi][nj] = MFMA16(aF[mi], bF[nj], acc5[mi][nj]);
    PRIO(0);
    BAR(); MEMFENCE();
  }

  unsigned short* ldsD = (unsigned short*)(lds + 65536);
  {
    float bv[2];
#pragma unroll
    for (int nj = 0; nj < 2; ++nj) bv[nj] = bd2[wid * 32 + nj * 16 + ln15];
#pragma unroll
    for (int mi = 0; mi < 4; ++mi) {
      int lrow = mi * 16 + kq * 4;
#pragma unroll
      for (int nj = 0; nj < 2; ++nj) {
        int col = wid * 32 + nj * 16 + ln15;
#pragma unroll
        for (int r = 0; r < 4; ++r) {
          float v = acc5[mi][nj][r] + bv[nj];
          v = v > 0.f ? v : 0.f;
          Df[(size_t)(bm + lrow + r) * 256 + col] = v;
          ldsD[(lrow + r) * 264 + col] = f2bf_bits(v);
        }
      }
    }
  }
  asm volatile("s_waitcnt lgkmcnt(0)");
  BAR(); MEMFENCE();

  // ---------------- head ----------------
  const int hrow = tid >> 3;
  const int he   = tid & 7;
  float s = 0.f;
  {
    const f32x4* wp = (const f32x4*)(wide + (size_t)(bm + hrow) * 256 + he * 32);
#pragma unroll
    for (int j = 0; j < 8; ++j) {
      f32x4 w = wp[j];
      s += w[0] + w[1] + w[2] + w[3];
    }
  }
  const int dm = dom[bm + hrow];
  {
    const f32x4* hp = (const f32x4*)(Wh + (size_t)dm * 256 + he * 32);
    const short8* dp = (const short8*)(ldsD + hrow * 264 + he * 32);
#pragma unroll
    for (int j = 0; j < 4; ++j) {
      short8 d8 = dp[j];
      f32x4 h0 = hp[2 * j], h1 = hp[2 * j + 1];
      s += bf_bits2f((unsigned short)d8[0]) * h0[0] +
           bf_bits2f((unsigned short)d8[1]) * h0[1] +
           bf_bits2f((unsigned short)d8[2]) * h0[2] +
           bf_bits2f((unsigned short)d8[3]) * h0[3] +
           bf_bits2f((unsigned short)d8[4]) * h1[0] +
           bf_bits2f((unsigned short)d8[5]) * h1[1] +
           bf_bits2f((unsigned short)d8[6]) * h1[2] +
           bf_bits2f((unsigned short)d8[7]) * h1[3];
    }
  }
  float* ldsH = (float*)(lds + 100352);
  ldsH[hrow * 8 + he] = s;
  asm volatile("s_waitcnt lgkmcnt(0)");
  BAR(); MEMFENCE();

  if (tid < 64) {
    float v = 0.f;
#pragma unroll
    for (int j = 0; j < 8; ++j) v += ldsH[tid * 8 + j];
    int dmr = dom[bm + tid];
    float x = v + bh[dmr];
    outp[bm + tid] = 1.f / (1.f + __expf(-x));
  }
}

// ---------------------------------------------------------------------------
extern "C" void kernel_launch(void* const* d_in, const int* in_sizes, int n_in,
                              void* d_out, int out_size, void* d_ws, size_t ws_size,
                              hipStream_t stream) {
  const float* wide = (const float*)d_in[0];
  const float* deep = (const float*)d_in[1];
  const int*   dom  = (const int*)d_in[2];
  const float* W1  = (const float*)d_in[3];
  const float* b1  = (const float*)d_in[4];
  const float* W2  = (const float*)d_in[5];
  const float* b2  = (const float*)d_in[6];
  const float* W3  = (const float*)d_in[7];
  const float* b3  = (const float*)d_in[8];
  const float* Wd1 = (const float*)d_in[9];
  const float* bd1 = (const float*)d_in[10];
  const float* Wd2 = (const float*)d_in[11];
  const float* bd2 = (const float*)d_in[12];
  const float* Wh  = (const float*)d_in[13];
  const float* bh  = (const float*)d_in[14];
  float* out = (float*)d_out;

  const int B = 16384;
  char* ws = (char*)d_ws;
  __hip_bfloat16* buf0 = (__hip_bfloat16*)ws;
  __hip_bfloat16* buf1 = (__hip_bfloat16*)(ws + 33554432ull);
  __hip_bfloat16* W1t  = (__hip_bfloat16*)(ws + 100663296ull);
  __hip_bfloat16* W2t  = W1t + 2048 * 1024;
  __hip_bfloat16* W3t  = W2t + 1024 * 2048;
  __hip_bfloat16* Wd1t = W3t + 512 * 1024;
  __hip_bfloat16* Wd2t = Wd1t + 512 * 512;

  prep<<<dim3(8192 + 1248), 256, 0, stream>>>(
      deep, (unsigned short*)buf0, W1, W1t, W2, W2t, W3, W3t, Wd1, Wd1t, Wd2, Wd2t);

  float* shared_out = out + B;
  float* d_out_f    = out + B + (size_t)B * 512;

  // L1: [B,1024]x[1024,2048] -> H1 (buf1)
  gemm_2c<<<dim3((2048 / 256) * (B / 256)), 512, 0, stream>>>(
      buf0, W1t, b1, buf1, nullptr, 2048, 1024, 2048 / 256);
  // L2: [B,2048]x[2048,1024] -> H2 (buf0)
  gemm_2c<<<dim3((1024 / 256) * (B / 256)), 512, 0, stream>>>(
      buf1, W2t, b2, buf0, nullptr, 1024, 2048, 1024 / 256);
  // L3+L4+L5+head fused
  tower<<<dim3(256), 512, 0, stream>>>(
      buf0, W3t, b3, Wd1t, bd1, Wd2t, bd2,
      shared_out, d_out_f, wide, dom, Wh, bh, out);
}